// Round 10
// baseline (162.847 us; speedup 1.0000x reference)
//
#include <hip/hip_runtime.h>
#include <hip/hip_bf16.h>

#define SS 2048
#define HH 1024
#define NHH 16
#define HDD 64

using f32x4  = __attribute__((ext_vector_type(4))) float;
using bf16x8 = __attribute__((ext_vector_type(8))) short;

#if __has_builtin(__builtin_amdgcn_exp2f)
#define EXP2F __builtin_amdgcn_exp2f
#else
#define EXP2F exp2f
#endif

__device__ __forceinline__ unsigned short f2bf(float f) {
    unsigned u = __builtin_bit_cast(unsigned, f);
    unsigned r = u + 0x7FFFu + ((u >> 16) & 1u);
    return (unsigned short)(r >> 16);
}

__device__ __forceinline__ unsigned bfround(float f) {
    unsigned u = __builtin_bit_cast(unsigned, f);
    return u + 0x7FFFu + ((u >> 16) & 1u);
}
// low16 = bf16(a) RNE, high16 = bf16(b) RNE — one v_perm_b32 after rounding
__device__ __forceinline__ unsigned pack2bf(float a, float b) {
    return __builtin_amdgcn_perm(bfround(b), bfround(a), 0x07060302u);
}
// truncating pack: raw high shorts, single v_perm_b32 (bias cancels in softmax ratio)
__device__ __forceinline__ unsigned pack2bf_trunc(float a, float b) {
    return __builtin_amdgcn_perm(__builtin_bit_cast(unsigned, b),
                                 __builtin_bit_cast(unsigned, a), 0x07060302u);
}

__device__ __forceinline__ void tetra(float t, float* c) {
    float a = 1.f / (1.f + __expf(-t));
    float na = 1.f - a;
    float nei = 1.f - (a + na);
    nei = fminf(fmaxf(nei, 0.f), 1.f);
    c[0] = a; c[1] = na; c[2] = a * na; c[3] = nei;
}

// async global->LDS, 16 B per lane. LDS dest is wave-uniform base (HW adds lane*16);
// global src is per-lane (carries the swizzle).
__device__ __forceinline__ void gll16(const unsigned short* g, unsigned short* l) {
    __builtin_amdgcn_global_load_lds(
        (const __attribute__((address_space(1))) unsigned int*)g,
        (__attribute__((address_space(3))) unsigned int*)l, 16, 0, 0);
}

// ---------------- cvt: fp32 -> bf16 for x, Wv, Wo; blocks >=2048 gather Wsel ----------------
__global__ __launch_bounds__(256) void cvt_kernel(
    const float* __restrict__ x, const float* __restrict__ Wv, const float* __restrict__ Wo,
    const float* __restrict__ Wq, const float* __restrict__ Wk,
    const float* __restrict__ bq, const float* __restrict__ bk,
    unsigned short* __restrict__ xb, unsigned short* __restrict__ Wvb, unsigned short* __restrict__ Wob,
    unsigned short* __restrict__ wselb, float* __restrict__ bselws)
{
    if (blockIdx.x >= 2048) {
        int n = blockIdx.x - 2048;
        int h = n >> 2, q = n & 3;
        int rowIdx = h * HDD + ((q & 1) ? 2 : 0);
        const float* src  = (q & 2) ? Wk : Wq;
        const float* bsrc = (q & 2) ? bk : bq;
        int t = threadIdx.x;
        float4 v = *(const float4*)(src + (size_t)rowIdx * HH + t * 4);
        uint2 pk;
        pk.x = pack2bf(v.x, v.y);
        pk.y = pack2bf(v.z, v.w);
        *(uint2*)(wselb + (size_t)n * HH + t * 4) = pk;
        if (t == 0) bselws[n] = bsrc[rowIdx];
        return;
    }
    size_t gid = (size_t)blockIdx.x * 256 + threadIdx.x;
    size_t base = gid * 8;
    {
        float4 a = *(const float4*)(x + base);
        float4 b = *(const float4*)(x + base + 4);
        uint4 pk;
        pk.x = pack2bf(a.x, a.y);
        pk.y = pack2bf(a.z, a.w);
        pk.z = pack2bf(b.x, b.y);
        pk.w = pack2bf(b.z, b.w);
        *(uint4*)(xb + base) = pk;
    }
    if (base < 1048576) {
        float4 a = *(const float4*)(Wv + base);
        float4 b = *(const float4*)(Wv + base + 4);
        uint4 pk;
        pk.x = pack2bf(a.x, a.y);
        pk.y = pack2bf(a.z, a.w);
        pk.z = pack2bf(b.x, b.y);
        pk.w = pack2bf(b.z, b.w);
        *(uint4*)(Wvb + base) = pk;
        a = *(const float4*)(Wo + base);
        b = *(const float4*)(Wo + base + 4);
        pk.x = pack2bf(a.x, a.y);
        pk.y = pack2bf(a.z, a.w);
        pk.z = pack2bf(b.x, b.y);
        pk.w = pack2bf(b.z, b.w);
        *(uint4*)(Wob + base) = pk;
    }
}

// ---------------- GEMM body v3 (R6-proven): 128x64 tile, 4 waves, BK=64 ----------------
// 2-phase dbuf global_load_lds + both-sides XOR chunk swizzle.
// OUT_MODE 0: fp32 row-major C. OUT_MODE 2: bf16 transposed into Vt[(bh*64+d)*SS + s].
template<int OUT_MODE>
__device__ __forceinline__ void gemm_body(unsigned char* smem,
    const unsigned short* __restrict__ A, const unsigned short* __restrict__ Bw,
    const float* __restrict__ bias, void* __restrict__ Cout, int bx, int by)
{
    int tid = threadIdx.x;
    int wave = tid >> 6, lane = tid & 63;
    int l15 = lane & 15, l16 = lane >> 4;
    int wm = wave >> 1, wn = wave & 1;
    int m0 = by * 128, n0 = bx * 64;

    // staging: lane -> (row = 8i + lane>>3, global chunk = (lane&7) ^ (lane>>3))
    int lrow = lane >> 3;
    int lcolsw = ((lane & 7) ^ lrow) * 8;
    const unsigned short* Ag = A + (size_t)(m0 + wave * 32 + lrow) * HH + lcolsw;
    const unsigned short* Bg = Bw + (size_t)(n0 + wave * 16 + lrow) * HH + lcolsw;

    f32x4 acc[4][2] = {};

    // prologue: stage tile 0 into buf 0
    {
        unsigned short* As = (unsigned short*)smem + (size_t)wave * 32 * 64;
        unsigned short* Bs = (unsigned short*)(smem + 16384) + (size_t)wave * 16 * 64;
        #pragma unroll
        for (int i = 0; i < 4; i++)
            gll16(Ag + (size_t)(i * 8) * HH, As + i * 8 * 64);
        #pragma unroll
        for (int i = 0; i < 2; i++)
            gll16(Bg + (size_t)(i * 8) * HH, Bs + i * 8 * 64);
    }
    __syncthreads();                                   // vmcnt(0) drain publishes tile 0

    int swq = l15 & 7;                                 // fragment row & 7
    int cur = 0;
    for (int k0 = 0; k0 < HH; k0 += 64) {
        // stage tile t+1 into the other buffer (overlaps with compute below)
        if (k0 + 64 < HH) {
            unsigned char* nb = smem + (cur ^ 1) * 24576;
            unsigned short* As = (unsigned short*)nb + (size_t)wave * 32 * 64;
            unsigned short* Bs = (unsigned short*)(nb + 16384) + (size_t)wave * 16 * 64;
            #pragma unroll
            for (int i = 0; i < 4; i++)
                gll16(Ag + (size_t)(i * 8) * HH + k0 + 64, As + i * 8 * 64);
            #pragma unroll
            for (int i = 0; i < 2; i++)
                gll16(Bg + (size_t)(i * 8) * HH + k0 + 64, Bs + i * 8 * 64);
        }

        unsigned char* cb = smem + cur * 24576;
        #pragma unroll
        for (int kk = 0; kk < 2; kk++) {
            int csw = ((kk * 4 + l16) ^ swq) * 16;     // swizzled 16B chunk
            bf16x8 af[4], bfr[2];
            #pragma unroll
            for (int mi = 0; mi < 4; mi++)
                af[mi] = *(const bf16x8*)(cb + (wm * 64 + mi * 16 + l15) * 128 + csw);
            #pragma unroll
            for (int ni = 0; ni < 2; ni++)
                bfr[ni] = *(const bf16x8*)(cb + 16384 + (wn * 32 + ni * 16 + l15) * 128 + csw);
            #pragma unroll
            for (int mi = 0; mi < 4; mi++)
                #pragma unroll
                for (int ni = 0; ni < 2; ni++)
                    acc[mi][ni] = __builtin_amdgcn_mfma_f32_16x16x32_bf16(af[mi], bfr[ni], acc[mi][ni], 0, 0, 0);
        }
        __syncthreads();                               // drains staged loads + guards reads
        cur ^= 1;
    }

    float bv[2];
    #pragma unroll
    for (int ni = 0; ni < 2; ni++)
        bv[ni] = bias[n0 + wn * 32 + ni * 16 + l15];

    #pragma unroll
    for (int mi = 0; mi < 4; mi++) {
        #pragma unroll
        for (int ni = 0; ni < 2; ni++) {
            int n = n0 + wn * 32 + ni * 16 + l15;
            if (OUT_MODE == 0) {
                #pragma unroll
                for (int r = 0; r < 4; r++) {
                    int m = m0 + wm * 64 + mi * 16 + l16 * 4 + r;
                    ((float*)Cout)[(size_t)m * HH + n] = acc[mi][ni][r] + bv[ni];
                }
            } else {
                int m = m0 + wm * 64 + mi * 16 + l16 * 4;
                int b = m >> 11, s = m & 2047;
                int h = n >> 6, d = n & 63;
                uint2 pk;
                pk.x = pack2bf(acc[mi][ni][0] + bv[ni], acc[mi][ni][1] + bv[ni]);
                pk.y = pack2bf(acc[mi][ni][2] + bv[ni], acc[mi][ni][3] + bv[ni]);
                *(uint2*)((unsigned short*)Cout + ((size_t)((b * NHH + h) * HDD + d)) * SS + s) = pk;
            }
        }
    }
}

// ---------------- qk body (R8 config: 32 m-rows, BK=64, exp2 scales) ----------------
__device__ __forceinline__ void qk_body(unsigned char* smem,
    const unsigned short* __restrict__ xb, const unsigned short* __restrict__ wselb,
    const float* __restrict__ bselws,
    unsigned short* __restrict__ qfb, unsigned short* __restrict__ kfb, int blk)
{
    auto xs = (unsigned short (*)[72])smem;             // [32][72]  (4608 B)
    auto ws = (unsigned short (*)[72])(smem + 4608);    // [64][72]  (9216 B)
    auto ys = (float (*)[68])(smem + 13824);            // [32][68]  (8704 B)
    int tid = threadIdx.x;
    int wave = tid >> 6, lane = tid & 63;
    int l15 = lane & 15, l16 = lane >> 4;
    int m0 = blk * 32;
    int n0w = wave * 16;

    int xr = tid >> 3, xseg = (tid & 7) * 8;
    int wr = tid >> 2, wseg = (tid & 3) * 16;
    const unsigned short* xp = xb + (size_t)(m0 + xr) * HH + xseg;
    const unsigned short* wp = wselb + (size_t)wr * HH + wseg;

    f32x4 acc[2] = {};

    uint4 xv  = *(const uint4*)(xp);
    uint4 wv0 = *(const uint4*)(wp);
    uint4 wv1 = *(const uint4*)(wp + 8);

    for (int k0 = 0; k0 < HH; k0 += 64) {
        __syncthreads();
        *(uint4*)&xs[xr][xseg] = xv;
        *(uint4*)&ws[wr][wseg]     = wv0;
        *(uint4*)&ws[wr][wseg + 8] = wv1;
        __syncthreads();

        int kn = (k0 + 64) & (HH - 1);
        uint4 nxv  = *(const uint4*)(xp + kn);
        uint4 nwv0 = *(const uint4*)(wp + kn);
        uint4 nwv1 = *(const uint4*)(wp + kn + 8);

        #pragma unroll
        for (int kk = 0; kk < 64; kk += 32) {
            bf16x8 bfr = *(const bf16x8*)&ws[n0w + l15][kk + l16 * 8];
            #pragma unroll
            for (int mi = 0; mi < 2; mi++) {
                bf16x8 af = *(const bf16x8*)&xs[mi * 16 + l15][kk + l16 * 8];
                acc[mi] = __builtin_amdgcn_mfma_f32_16x16x32_bf16(af, bfr, acc[mi], 0, 0, 0);
            }
        }
        xv = nxv; wv0 = nwv0; wv1 = nwv1;
    }

    float bias = bselws[n0w + l15];
    __syncthreads();
    #pragma unroll
    for (int mi = 0; mi < 2; mi++)
        #pragma unroll
        for (int r = 0; r < 4; r++)
            ys[mi * 16 + l16 * 4 + r][n0w + l15] = acc[mi][r] + bias;
    __syncthreads();

    #pragma unroll
    for (int pass = 0; pass < 2; pass++) {
        int ml = tid & 31;
        int h = (tid >> 5) + pass * 8;
        float4 y4 = *(const float4*)&ys[ml][h * 4];
        float qa[4], qb2[4], ka[4], kb2[4];
        tetra(y4.x, qa);
        tetra(y4.y, qb2);
        tetra(y4.z, ka);
        tetra(y4.w, kb2);
        int m = m0 + ml, b = m >> 11, s = m & 2047;
        size_t base = ((size_t)(b * NHH + h) * SS + s) * 8;
        const float sA = 0.18033688011112042f;   // 0.125 * log2(e)
        const float sB = 0.14426950408889634f;   // 0.1   * log2(e)
        uint4 qp, kp;
        qp.x = pack2bf(qa[0] * sA, qa[1] * sA);
        qp.y = pack2bf(qa[2] * sA, qa[3] * sA);
        qp.z = pack2bf(qb2[0] * sB, qb2[1] * sB);
        qp.w = pack2bf(qb2[2] * sB, qb2[3] * sB);
        kp.x = pack2bf(ka[0], ka[1]);
        kp.y = pack2bf(ka[2], ka[3]);
        kp.z = pack2bf(kb2[0], kb2[1]);
        kp.w = pack2bf(kb2[2], kb2[3]);
        *(uint4*)(qfb + base) = qp;
        *(uint4*)(kfb + base) = kp;
    }
}

// ---------------- fused mid kernel: logical 0-511 = V-GEMM, 512-639 = qk (R6) ----------
__global__ __launch_bounds__(256) void fused_mid(
    const unsigned short* __restrict__ xb,
    const unsigned short* __restrict__ Wvb, const float* __restrict__ bv,
    unsigned short* __restrict__ Vt,
    const unsigned short* __restrict__ wselb, const float* __restrict__ bselws,
    unsigned short* __restrict__ qfb, unsigned short* __restrict__ kfb)
{
    __shared__ __align__(16) unsigned char smem[49152];
    int p = blockIdx.x;
    if (p < 512) {
        int id = (p & 7) * 64 + (p >> 3);               // 512 = 8*64, bijective
        gemm_body<2>(smem, xb, Wvb, bv, Vt, id & 15, id >> 4);
    } else {
        int q = p - 512;
        int id = (q & 7) * 16 + (q >> 3);               // 128 = 8*16, bijective
        qk_body(smem, xb, wselb, bselws, qfb, kfb, id);
    }
}

// ---------------- standalone O-projection GEMM (1D grid 512, XCD-chunked, R6) ----------
__global__ __launch_bounds__(256) void gemm_out(
    const unsigned short* __restrict__ A, const unsigned short* __restrict__ Bw,
    const float* __restrict__ bias, float* __restrict__ Cout)
{
    __shared__ __align__(16) unsigned char smem[49152];
    int p = blockIdx.x;
    int id = (p & 7) * 64 + (p >> 3);                   // 512 = 8*64, bijective
    gemm_body<0>(smem, A, Bw, bias, Cout, id & 15, id >> 4);
}

// ---------------- MFMA flash attention v4.2: 8-wave KV-split + gll16 V staging ----------
// R6 structure; V staging now via global_load_lds (no VGPR round-trip, no ds_write):
// wave w stages rows w*8..w*8+7 of BOTH halves' next tile. LDS dest wave-uniform
// (lds + half*16384 + buf*8192 + wave*1024; HW adds lane*16); global src pre-swizzled
// chunk = (lane&7)^(lane>>3), so LDS slot s of row d holds global chunk s^(d&7) —
// identical layout to before; PV read side unchanged. Loads issued right after the
// top barrier get a full iteration of latency cover; end-of-iter barrier drains them.
__global__ __launch_bounds__(512) void attn_mfma(
    const unsigned short* __restrict__ qfb, const unsigned short* __restrict__ kfb,
    const unsigned short* __restrict__ Vt, unsigned short* __restrict__ attnb)
{
    __shared__ __align__(16) unsigned char lds[65536];

    int tid = threadIdx.x;
    int wave = tid >> 6, lane = tid & 63;
    int sub = wave & 3, hf = wave >> 2;
    int l15 = lane & 15, l16 = lane >> 4;
    int l7 = l15 & 7;

    int L = blockIdx.x + (blockIdx.y << 4);        // 0..511
    int logical = ((L & 7) << 6) + (L >> 3);
    int bh = logical >> 4, qblk = logical & 15;
    int b = bh >> 4, h = bh & 15;
    int s0 = qblk * 128 + sub * 32;                // this wave-pair's 32 q

    bf16x8 qA = {0,0,0,0,0,0,0,0}, qB = {0,0,0,0,0,0,0,0};
    if (l16 == 0) {
        qA = *(const bf16x8*)(qfb + ((size_t)bh * SS + s0 + l15) * 8);
        qB = *(const bf16x8*)(qfb + ((size_t)bh * SS + s0 + 16 + l15) * 8);
    }

    const short oneb = 0x3F80;                     // bf16 1.0
    bf16x8 ones = {oneb,oneb,oneb,oneb,oneb,oneb,oneb,oneb};

    const unsigned short* kfA = kfb + ((size_t)bh * SS + hf * 1024 + l15) * 8;

    // V staging (gll16): row d = wave*8 + (lane>>3), swizzled global chunk
    const unsigned short* vsrcg = Vt + ((size_t)bh * HDD + wave * 8 + (lane >> 3)) * SS
                                + ((lane & 7) ^ (lane >> 3)) * 8;
    unsigned short* vdst0 = (unsigned short*)lds + wave * 512;          // half 0 base
    unsigned short* vdst1 = (unsigned short*)lds + 8192 + wave * 512;   // half 1 base

    unsigned char* psw = lds + 32768 + wave * 4096;   // wave-private P [32 q][128 B]

    f32x4 acc[2][4] = {};
    f32x4 accl[2] = {};

    // prologue: issue local tile 0 of both halves into buf 0 (drained by iter-0 barrier)
    gll16(vsrcg, vdst0);
    gll16(vsrcg + 1024, vdst1);

    bf16x8 kfr[4];
    #pragma unroll
    for (int tb = 0; tb < 4; tb++)
        kfr[tb] = *(const bf16x8*)(kfA + (size_t)(tb * 16) * 8);

    for (int it = 0; it < 16; it++) {
        __syncthreads();                           // drains tile-it loads; WAR for buf[(it+1)&1]

        // issue tile it+1 of both halves into the other buffer (async, covered by this iter)
        if (it < 15) {
            int tn = (it + 1) << 6;
            int nb2 = ((it + 1) & 1) * 4096;       // buf offset in shorts (8192 B)
            gll16(vsrcg + tn, vdst0 + nb2);
            gll16(vsrcg + 1024 + tn, vdst1 + nb2);
        }

        int tkf = ((it + 1) & 15) << 6;
        bf16x8 nkf[4];
        #pragma unroll
        for (int tb = 0; tb < 4; tb++)
            nkf[tb] = *(const bf16x8*)(kfA + (size_t)(tkf + tb * 16) * 8);

        #pragma unroll
        for (int g = 0; g < 2; g++) {
            bf16x8 qf = g ? qB : qA;
            #pragma unroll
            for (int tb = 0; tb < 4; tb++) {
                f32x4 sc = {};
                sc = __builtin_amdgcn_mfma_f32_16x16x32_bf16(kfr[tb], qf, sc, 0, 0, 0);
                uint2 pw;
                pw.x = pack2bf_trunc(EXP2F(sc[0]), EXP2F(sc[1]));
                pw.y = pack2bf_trunc(EXP2F(sc[2]), EXP2F(sc[3]));
                int qr = g * 16 + l15;
                int c  = (tb * 2 + (l16 >> 1)) ^ l7;
                *(uint2*)(psw + qr * 128 + c * 16 + (l16 & 1) * 8) = pw;
            }
        }

        unsigned char* vbuf = lds + hf * 16384 + (it & 1) * 8192;
        __builtin_amdgcn_s_setprio(1);
        #pragma unroll
        for (int tk = 0; tk < 2; tk++) {
            int csw = ((tk * 4 + l16) ^ l7) << 4;
            bf16x8 apA = *(const bf16x8*)(psw + l15 * 128 + csw);
            bf16x8 apB = *(const bf16x8*)(psw + (16 + l15) * 128 + csw);
            accl[0] = __builtin_amdgcn_mfma_f32_16x16x32_bf16(apA, ones, accl[0], 0, 0, 0);
            accl[1] = __builtin_amdgcn_mfma_f32_16x16x32_bf16(apB, ones, accl[1], 0, 0, 0);
            #pragma unroll
            for (int nd = 0; nd < 4; nd++) {
                bf16x8 bv = *(const bf16x8*)(vbuf + (nd * 16 + l15) * 128 + csw);
                acc[0][nd] = __builtin_amdgcn_mfma_f32_16x16x32_bf16(apA, bv, acc[0][nd], 0, 0, 0);
                acc[1][nd] = __builtin_amdgcn_mfma_f32_16x16x32_bf16(apB, bv, acc[1][nd], 0, 0, 0);
            }
        }
        __builtin_amdgcn_s_setprio(0);

        #pragma unroll
        for (int tb = 0; tb < 4; tb++) kfr[tb] = nkf[tb];
    }

    // ---- combine halves: waves 4-7 hand their partials to waves 0-3 via LDS
    __syncthreads();                               // also drains any stray staged loads
    float* xch = (float*)lds;
    if (wave >= 4) {
        float* dst = xch + ((size_t)((wave - 4) * 64 + lane)) * 40;
        #pragma unroll
        for (int g = 0; g < 2; g++)
            #pragma unroll
            for (int nd = 0; nd < 4; nd++)
                *(f32x4*)(dst + (g * 4 + nd) * 4) = acc[g][nd];
        *(f32x4*)(dst + 32) = accl[0];
        *(f32x4*)(dst + 36) = accl[1];
    }
    __syncthreads();
    if (wave < 4) {
        float* src = xch + ((size_t)(wave * 64 + lane)) * 40;
        #pragma unroll
        for (int g = 0; g < 2; g++)
            #pragma unroll
            for (int nd = 0; nd < 4; nd++)
                acc[g][nd] += *(const f32x4*)(src + (g * 4 + nd) * 4);
        accl[0] += *(const f32x4*)(src + 32);
        accl[1] += *(const f32x4*)(src + 36);

        #pragma unroll
        for (int g = 0; g < 2; g++) {
            #pragma unroll
            for (int r = 0; r < 4; r++) {
                float linv = 1.f / accl[g][r];
                int q = s0 + g * 16 + l16 * 4 + r;
                size_t row = (size_t)(b * SS + q) * HH + h * HDD;
                #pragma unroll
                for (int nd = 0; nd < 4; nd++)
                    attnb[row + nd * 16 + l15] = f2bf(acc[g][nd][r] * linv);
            }
        }
    }
}

extern "C" void kernel_launch(void* const* d_in, const int* in_sizes, int n_in,
                              void* d_out, int out_size, void* d_ws, size_t ws_size,
                              hipStream_t stream)
{
    const float* x  = (const float*)d_in[0];
    const float* Wq = (const float*)d_in[1];
    const float* Wk = (const float*)d_in[2];
    const float* Wv = (const float*)d_in[3];
    const float* Wo = (const float*)d_in[4];
    const float* bq = (const float*)d_in[5];
    const float* bk = (const float*)d_in[6];
    const float* bv = (const float*)d_in[7];
    const float* bo = (const float*)d_in[8];

    unsigned short* qfb   = (unsigned short*)d_ws;     // 524288
    unsigned short* kfb   = qfb + 524288;              // 524288
    unsigned short* xb    = kfb + 524288;              // 4194304 (aliased w/ attnb)
    unsigned short* attnb = xb;                        // alias: xb dead after fused_mid
    unsigned short* Wvb   = xb + 4194304;              // 1048576
    unsigned short* Wob   = Wvb + 1048576;             // 1048576
    unsigned short* Vt    = Wob + 1048576;             // 4194304
    unsigned short* wselb  = Vt + 4194304;             // 65536
    float*          bselws = (float*)(wselb + 65536);  // 64

    cvt_kernel<<<2112, 256, 0, stream>>>(x, Wv, Wo, Wq, Wk, bq, bk, xb, Wvb, Wob, wselb, bselws);
    fused_mid<<<640, 256, 0, stream>>>(xb, Wvb, bv, Vt, wselb, bselws, qfb, kfb);
    attn_mfma<<<dim3(16, 32), 512, 0, stream>>>(qfb, kfb, Vt, attnb);
    gemm_out<<<512, 256, 0, stream>>>(attnb, Wob, bo, (float*)d_out);
}

// Round 11
// 149.371 us; speedup vs baseline: 1.0902x; 1.0902x over previous
//
#include <hip/hip_runtime.h>
#include <hip/hip_bf16.h>

#define SS 2048
#define HH 1024
#define NHH 16
#define HDD 64

using f32x4  = __attribute__((ext_vector_type(4))) float;
using bf16x8 = __attribute__((ext_vector_type(8))) short;

#if __has_builtin(__builtin_amdgcn_exp2f)
#define EXP2F __builtin_amdgcn_exp2f
#else
#define EXP2F exp2f
#endif

__device__ __forceinline__ unsigned short f2bf(float f) {
    unsigned u = __builtin_bit_cast(unsigned, f);
    unsigned r = u + 0x7FFFu + ((u >> 16) & 1u);
    return (unsigned short)(r >> 16);
}

__device__ __forceinline__ unsigned bfround(float f) {
    unsigned u = __builtin_bit_cast(unsigned, f);
    return u + 0x7FFFu + ((u >> 16) & 1u);
}
// low16 = bf16(a) RNE, high16 = bf16(b) RNE — one v_perm_b32 after rounding
__device__ __forceinline__ unsigned pack2bf(float a, float b) {
    return __builtin_amdgcn_perm(bfround(b), bfround(a), 0x07060302u);
}
// truncating pack: raw high shorts, single v_perm_b32 (bias cancels in softmax ratio)
__device__ __forceinline__ unsigned pack2bf_trunc(float a, float b) {
    return __builtin_amdgcn_perm(__builtin_bit_cast(unsigned, b),
                                 __builtin_bit_cast(unsigned, a), 0x07060302u);
}

__device__ __forceinline__ void tetra(float t, float* c) {
    float a = 1.f / (1.f + __expf(-t));
    float na = 1.f - a;
    float nei = 1.f - (a + na);
    nei = fminf(fmaxf(nei, 0.f), 1.f);
    c[0] = a; c[1] = na; c[2] = a * na; c[3] = nei;
}

// async global->LDS, 16 B per lane. LDS dest is wave-uniform base + lane*16;
// global src is per-lane (carries the swizzle).
__device__ __forceinline__ void gll16(const unsigned short* g, unsigned short* l) {
    __builtin_amdgcn_global_load_lds(
        (const __attribute__((address_space(1))) unsigned int*)g,
        (__attribute__((address_space(3))) unsigned int*)l, 16, 0, 0);
}

// ---------------- cvt: fp32 -> bf16 for x, Wv, Wo; blocks >=2048 gather Wsel ----------------
__global__ __launch_bounds__(256) void cvt_kernel(
    const float* __restrict__ x, const float* __restrict__ Wv, const float* __restrict__ Wo,
    const float* __restrict__ Wq, const float* __restrict__ Wk,
    const float* __restrict__ bq, const float* __restrict__ bk,
    unsigned short* __restrict__ xb, unsigned short* __restrict__ Wvb, unsigned short* __restrict__ Wob,
    unsigned short* __restrict__ wselb, float* __restrict__ bselws)
{
    if (blockIdx.x >= 2048) {
        int n = blockIdx.x - 2048;
        int h = n >> 2, q = n & 3;
        int rowIdx = h * HDD + ((q & 1) ? 2 : 0);
        const float* src  = (q & 2) ? Wk : Wq;
        const float* bsrc = (q & 2) ? bk : bq;
        int t = threadIdx.x;
        float4 v = *(const float4*)(src + (size_t)rowIdx * HH + t * 4);
        uint2 pk;
        pk.x = pack2bf(v.x, v.y);
        pk.y = pack2bf(v.z, v.w);
        *(uint2*)(wselb + (size_t)n * HH + t * 4) = pk;
        if (t == 0) bselws[n] = bsrc[rowIdx];
        return;
    }
    size_t gid = (size_t)blockIdx.x * 256 + threadIdx.x;
    size_t base = gid * 8;
    {
        float4 a = *(const float4*)(x + base);
        float4 b = *(const float4*)(x + base + 4);
        uint4 pk;
        pk.x = pack2bf(a.x, a.y);
        pk.y = pack2bf(a.z, a.w);
        pk.z = pack2bf(b.x, b.y);
        pk.w = pack2bf(b.z, b.w);
        *(uint4*)(xb + base) = pk;
    }
    if (base < 1048576) {
        float4 a = *(const float4*)(Wv + base);
        float4 b = *(const float4*)(Wv + base + 4);
        uint4 pk;
        pk.x = pack2bf(a.x, a.y);
        pk.y = pack2bf(a.z, a.w);
        pk.z = pack2bf(b.x, b.y);
        pk.w = pack2bf(b.z, b.w);
        *(uint4*)(Wvb + base) = pk;
        a = *(const float4*)(Wo + base);
        b = *(const float4*)(Wo + base + 4);
        pk.x = pack2bf(a.x, a.y);
        pk.y = pack2bf(a.z, a.w);
        pk.z = pack2bf(b.x, b.y);
        pk.w = pack2bf(b.z, b.w);
        *(uint4*)(Wob + base) = pk;
    }
}

// ---------------- GEMM body v3: 128x64 tile, BK=64, dbuf global_load_lds + XOR swizzle ----
// Minimum 2-phase: STAGE(t+1) -> compute(t) -> one barrier (implicit vmcnt(0) publishes).
// LDS linear rows of 64 shorts (128 B); 16B chunk c swizzled c^=(row&7) on BOTH the
// per-lane global source (staging) and the ds_read side -> conflict-free b128 reads.
// OUT_MODE 0: fp32 row-major C. OUT_MODE 2: bf16 transposed into Vt[(bh*64+d)*SS + s].
template<int OUT_MODE>
__device__ __forceinline__ void gemm_body(unsigned char* smem,
    const unsigned short* __restrict__ A, const unsigned short* __restrict__ Bw,
    const float* __restrict__ bias, void* __restrict__ Cout, int bx, int by)
{
    int tid = threadIdx.x;
    int wave = tid >> 6, lane = tid & 63;
    int l15 = lane & 15, l16 = lane >> 4;
    int wm = wave >> 1, wn = wave & 1;
    int m0 = by * 128, n0 = bx * 64;

    // staging: lane -> (row = 8i + lane>>3, global chunk = (lane&7) ^ (lane>>3))
    int lrow = lane >> 3;
    int lcolsw = ((lane & 7) ^ lrow) * 8;
    const unsigned short* Ag = A + (size_t)(m0 + wave * 32 + lrow) * HH + lcolsw;
    const unsigned short* Bg = Bw + (size_t)(n0 + wave * 16 + lrow) * HH + lcolsw;

    f32x4 acc[4][2] = {};

    // prologue: stage tile 0 into buf 0
    {
        unsigned short* As = (unsigned short*)smem + (size_t)wave * 32 * 64;
        unsigned short* Bs = (unsigned short*)(smem + 16384) + (size_t)wave * 16 * 64;
        #pragma unroll
        for (int i = 0; i < 4; i++)
            gll16(Ag + (size_t)(i * 8) * HH, As + i * 8 * 64);
        #pragma unroll
        for (int i = 0; i < 2; i++)
            gll16(Bg + (size_t)(i * 8) * HH, Bs + i * 8 * 64);
    }
    __syncthreads();                                   // vmcnt(0) drain publishes tile 0

    int swq = l15 & 7;                                 // fragment row & 7
    int cur = 0;
    for (int k0 = 0; k0 < HH; k0 += 64) {
        // stage tile t+1 into the other buffer (overlaps with compute below)
        if (k0 + 64 < HH) {
            unsigned char* nb = smem + (cur ^ 1) * 24576;
            unsigned short* As = (unsigned short*)nb + (size_t)wave * 32 * 64;
            unsigned short* Bs = (unsigned short*)(nb + 16384) + (size_t)wave * 16 * 64;
            #pragma unroll
            for (int i = 0; i < 4; i++)
                gll16(Ag + (size_t)(i * 8) * HH + k0 + 64, As + i * 8 * 64);
            #pragma unroll
            for (int i = 0; i < 2; i++)
                gll16(Bg + (size_t)(i * 8) * HH + k0 + 64, Bs + i * 8 * 64);
        }

        unsigned char* cb = smem + cur * 24576;
        #pragma unroll
        for (int kk = 0; kk < 2; kk++) {
            int csw = ((kk * 4 + l16) ^ swq) * 16;     // swizzled 16B chunk
            bf16x8 af[4], bfr[2];
            #pragma unroll
            for (int mi = 0; mi < 4; mi++)
                af[mi] = *(const bf16x8*)(cb + (wm * 64 + mi * 16 + l15) * 128 + csw);
            #pragma unroll
            for (int ni = 0; ni < 2; ni++)
                bfr[ni] = *(const bf16x8*)(cb + 16384 + (wn * 32 + ni * 16 + l15) * 128 + csw);
            #pragma unroll
            for (int mi = 0; mi < 4; mi++)
                #pragma unroll
                for (int ni = 0; ni < 2; ni++)
                    acc[mi][ni] = __builtin_amdgcn_mfma_f32_16x16x32_bf16(af[mi], bfr[ni], acc[mi][ni], 0, 0, 0);
        }
        __syncthreads();                               // drains staged loads + guards reads
        cur ^= 1;
    }

    float bv[2];
    #pragma unroll
    for (int ni = 0; ni < 2; ni++)
        bv[ni] = bias[n0 + wn * 32 + ni * 16 + l15];

    #pragma unroll
    for (int mi = 0; mi < 4; mi++) {
        #pragma unroll
        for (int ni = 0; ni < 2; ni++) {
            int n = n0 + wn * 32 + ni * 16 + l15;
            if (OUT_MODE == 0) {
                #pragma unroll
                for (int r = 0; r < 4; r++) {
                    int m = m0 + wm * 64 + mi * 16 + l16 * 4 + r;
                    ((float*)Cout)[(size_t)m * HH + n] = acc[mi][ni][r] + bv[ni];
                }
            } else {
                int m = m0 + wm * 64 + mi * 16 + l16 * 4;
                int b = m >> 11, s = m & 2047;
                int h = n >> 6, d = n & 63;
                uint2 pk;
                pk.x = pack2bf(acc[mi][ni][0] + bv[ni], acc[mi][ni][1] + bv[ni]);
                pk.y = pack2bf(acc[mi][ni][2] + bv[ni], acc[mi][ni][3] + bv[ni]);
                *(uint2*)((unsigned short*)Cout + ((size_t)((b * NHH + h) * HDD + d)) * SS + s) = pk;
            }
        }
    }
}

// ---------------- qk body (R8 config: 32 m-rows, BK=64, exp2 scales) ----------------
__device__ __forceinline__ void qk_body(unsigned char* smem,
    const unsigned short* __restrict__ xb, const unsigned short* __restrict__ wselb,
    const float* __restrict__ bselws,
    unsigned short* __restrict__ qfb, unsigned short* __restrict__ kfb, int blk)
{
    auto xs = (unsigned short (*)[72])smem;             // [32][72]  (4608 B)
    auto ws = (unsigned short (*)[72])(smem + 4608);    // [64][72]  (9216 B)
    auto ys = (float (*)[68])(smem + 13824);            // [32][68]  (8704 B)
    int tid = threadIdx.x;
    int wave = tid >> 6, lane = tid & 63;
    int l15 = lane & 15, l16 = lane >> 4;
    int m0 = blk * 32;
    int n0w = wave * 16;

    int xr = tid >> 3, xseg = (tid & 7) * 8;
    int wr = tid >> 2, wseg = (tid & 3) * 16;
    const unsigned short* xp = xb + (size_t)(m0 + xr) * HH + xseg;
    const unsigned short* wp = wselb + (size_t)wr * HH + wseg;

    f32x4 acc[2] = {};

    uint4 xv  = *(const uint4*)(xp);
    uint4 wv0 = *(const uint4*)(wp);
    uint4 wv1 = *(const uint4*)(wp + 8);

    for (int k0 = 0; k0 < HH; k0 += 64) {
        __syncthreads();
        *(uint4*)&xs[xr][xseg] = xv;
        *(uint4*)&ws[wr][wseg]     = wv0;
        *(uint4*)&ws[wr][wseg + 8] = wv1;
        __syncthreads();

        int kn = (k0 + 64) & (HH - 1);
        uint4 nxv  = *(const uint4*)(xp + kn);
        uint4 nwv0 = *(const uint4*)(wp + kn);
        uint4 nwv1 = *(const uint4*)(wp + kn + 8);

        #pragma unroll
        for (int kk = 0; kk < 64; kk += 32) {
            bf16x8 bfr = *(const bf16x8*)&ws[n0w + l15][kk + l16 * 8];
            #pragma unroll
            for (int mi = 0; mi < 2; mi++) {
                bf16x8 af = *(const bf16x8*)&xs[mi * 16 + l15][kk + l16 * 8];
                acc[mi] = __builtin_amdgcn_mfma_f32_16x16x32_bf16(af, bfr, acc[mi], 0, 0, 0);
            }
        }
        xv = nxv; wv0 = nwv0; wv1 = nwv1;
    }

    float bias = bselws[n0w + l15];
    __syncthreads();
    #pragma unroll
    for (int mi = 0; mi < 2; mi++)
        #pragma unroll
        for (int r = 0; r < 4; r++)
            ys[mi * 16 + l16 * 4 + r][n0w + l15] = acc[mi][r] + bias;
    __syncthreads();

    #pragma unroll
    for (int pass = 0; pass < 2; pass++) {
        int ml = tid & 31;
        int h = (tid >> 5) + pass * 8;
        float4 y4 = *(const float4*)&ys[ml][h * 4];
        float qa[4], qb2[4], ka[4], kb2[4];
        tetra(y4.x, qa);
        tetra(y4.y, qb2);
        tetra(y4.z, ka);
        tetra(y4.w, kb2);
        int m = m0 + ml, b = m >> 11, s = m & 2047;
        size_t base = ((size_t)(b * NHH + h) * SS + s) * 8;
        const float sA = 0.18033688011112042f;   // 0.125 * log2(e)
        const float sB = 0.14426950408889634f;   // 0.1   * log2(e)
        uint4 qp, kp;
        qp.x = pack2bf(qa[0] * sA, qa[1] * sA);
        qp.y = pack2bf(qa[2] * sA, qa[3] * sA);
        qp.z = pack2bf(qb2[0] * sB, qb2[1] * sB);
        qp.w = pack2bf(qb2[2] * sB, qb2[3] * sB);
        kp.x = pack2bf(ka[0], ka[1]);
        kp.y = pack2bf(ka[2], ka[3]);
        kp.z = pack2bf(kb2[0], kb2[1]);
        kp.w = pack2bf(kb2[2], kb2[3]);
        *(uint4*)(qfb + base) = qp;
        *(uint4*)(kfb + base) = kp;
    }
}

// ---------------- fused mid kernel: logical 0-511 = V-GEMM, 512-639 = qk ----------------
// Class-preserving XCD-chunked remap: gemm ids and qk ids each spread over all 8 XCDs
// (so light qk blocks don't cluster on two XCDs), contiguous panels per XCD for L2.
__global__ __launch_bounds__(256) void fused_mid(
    const unsigned short* __restrict__ xb,
    const unsigned short* __restrict__ Wvb, const float* __restrict__ bv,
    unsigned short* __restrict__ Vt,
    const unsigned short* __restrict__ wselb, const float* __restrict__ bselws,
    unsigned short* __restrict__ qfb, unsigned short* __restrict__ kfb)
{
    __shared__ __align__(16) unsigned char smem[49152];
    int p = blockIdx.x;
    if (p < 512) {
        int id = (p & 7) * 64 + (p >> 3);               // 512 = 8*64, bijective
        gemm_body<2>(smem, xb, Wvb, bv, Vt, id & 15, id >> 4);
    } else {
        int q = p - 512;
        int id = (q & 7) * 16 + (q >> 3);               // 128 = 8*16, bijective
        qk_body(smem, xb, wselb, bselws, qfb, kfb, id);
    }
}

// ---------------- standalone O-projection GEMM (1D grid 512, XCD-chunked) ----------------
__global__ __launch_bounds__(256) void gemm_out(
    const unsigned short* __restrict__ A, const unsigned short* __restrict__ Bw,
    const float* __restrict__ bias, float* __restrict__ Cout)
{
    __shared__ __align__(16) unsigned char smem[49152];
    int p = blockIdx.x;
    int id = (p & 7) * 64 + (p >> 3);                   // 512 = 8*64, bijective
    gemm_body<0>(smem, A, Bw, bias, Cout, id & 15, id >> 4);
}

// ---------------- MFMA flash attention v4: 8-wave in-block KV-split (R6 best) ----------
// 512 threads. Waves 0-3: KV tiles 0..15; waves 4-7: KV tiles 16..31. Wave w and w+4
// own the SAME 32 q (sub = w&3); exp2 has no running max so partials combine linearly
// (acc/accl summed via one LDS exchange at the end; waves 0-3 normalize + store).
// LDS 64K: vt [2 half][2 dbuf][64][128B] = 32K @0, ps 8 waves x 4K = 32K @32768.
// One barrier/iter guards vt only; ps is wave-private. V reg-staged (2-iter window).
__global__ __launch_bounds__(512) void attn_mfma(
    const unsigned short* __restrict__ qfb, const unsigned short* __restrict__ kfb,
    const unsigned short* __restrict__ Vt, unsigned short* __restrict__ attnb)
{
    __shared__ __align__(16) unsigned char lds[65536];

    int tid = threadIdx.x;
    int wave = tid >> 6, lane = tid & 63;
    int sub = wave & 3, hf = wave >> 2;
    int l15 = lane & 15, l16 = lane >> 4;
    int l7 = l15 & 7;

    int L = blockIdx.x + (blockIdx.y << 4);        // 0..511
    int logical = ((L & 7) << 6) + (L >> 3);
    int bh = logical >> 4, qblk = logical & 15;
    int b = bh >> 4, h = bh & 15;
    int s0 = qblk * 128 + sub * 32;                // this wave-pair's 32 q

    bf16x8 qA = {0,0,0,0,0,0,0,0}, qB = {0,0,0,0,0,0,0,0};
    if (l16 == 0) {
        qA = *(const bf16x8*)(qfb + ((size_t)bh * SS + s0 + l15) * 8);
        qB = *(const bf16x8*)(qfb + ((size_t)bh * SS + s0 + 16 + l15) * 8);
    }

    const short oneb = 0x3F80;                     // bf16 1.0
    bf16x8 ones = {oneb,oneb,oneb,oneb,oneb,oneb,oneb,oneb};

    // this wave's kf base: its KV half
    const unsigned short* kfA = kfb + ((size_t)bh * SS + hf * 1024 + l15) * 8;

    // vt staging: this thread covers row vd, 32B at chunks vr*2, vr*2+1 of its half's tile
    int t8 = tid & 255, shf = tid >> 8;            // staging half (== hf since wave>>2 == tid>>8)
    int vd = t8 >> 2, vr = t8 & 3;
    const unsigned short* vsrc = Vt + ((size_t)bh * HDD + vd) * SS + shf * 1024 + vr * 16;

    unsigned char* vrow = lds + shf * 16384 + vd * 128;
    int sw0 = ((vr * 2)     ^ (vd & 7)) << 4;
    int sw1 = ((vr * 2 + 1) ^ (vd & 7)) << 4;
    unsigned char* psw = lds + 32768 + wave * 4096;   // wave-private P [32 q][128 B]

    f32x4 acc[2][4] = {};
    f32x4 accl[2] = {};

    // prologue: local tile 0 -> buf 0 (published by iter-0 barrier)
    {
        uint4 t0a = *(const uint4*)(vsrc);
        uint4 t0b = *(const uint4*)(vsrc + 8);
        *(uint4*)(vrow + sw0) = t0a;
        *(uint4*)(vrow + sw1) = t0b;
    }
    uint4 sv0 = *(const uint4*)(vsrc + 64);        // local tile 1
    uint4 sv1 = *(const uint4*)(vsrc + 64 + 8);
    bf16x8 kfr[4];
    #pragma unroll
    for (int tb = 0; tb < 4; tb++)
        kfr[tb] = *(const bf16x8*)(kfA + (size_t)(tb * 16) * 8);

    for (int it = 0; it < 16; it++) {
        __syncthreads();                           // publishes vt(it); WAR for buf[(it+1)&1]

        // write local tile it+1 into the other buffer (wrapped on tail, then unused)
        int nb = (it + 1) & 1;
        *(uint4*)(vrow + nb * 8192 + sw0) = sv0;
        *(uint4*)(vrow + nb * 8192 + sw1) = sv1;

        // prefetch local tile it+2 (V) and it+1 (kf), wrapped
        int tv = ((it + 2) & 15) << 6;
        uint4 nv0 = *(const uint4*)(vsrc + tv);
        uint4 nv1 = *(const uint4*)(vsrc + tv + 8);
        int tkf = ((it + 1) & 15) << 6;
        bf16x8 nkf[4];
        #pragma unroll
        for (int tb = 0; tb < 4; tb++)
            nkf[tb] = *(const bf16x8*)(kfA + (size_t)(tkf + tb * 16) * 8);

        // ---- QK(it): scores -> exp2 -> truncated bf16 P into ps (wave-private)
        #pragma unroll
        for (int g = 0; g < 2; g++) {
            bf16x8 qf = g ? qB : qA;
            #pragma unroll
            for (int tb = 0; tb < 4; tb++) {
                f32x4 sc = {};
                sc = __builtin_amdgcn_mfma_f32_16x16x32_bf16(kfr[tb], qf, sc, 0, 0, 0);
                uint2 pw;
                pw.x = pack2bf_trunc(EXP2F(sc[0]), EXP2F(sc[1]));
                pw.y = pack2bf_trunc(EXP2F(sc[2]), EXP2F(sc[3]));
                int qr = g * 16 + l15;
                int c  = (tb * 2 + (l16 >> 1)) ^ l7;
                *(uint2*)(psw + qr * 128 + c * 16 + (l16 & 1) * 8) = pw;
            }
        }

        // ---- PV(it) from this half's vt buf[it&1]
        unsigned char* vbuf = lds + hf * 16384 + (it & 1) * 8192;
        __builtin_amdgcn_s_setprio(1);
        #pragma unroll
        for (int tk = 0; tk < 2; tk++) {
            int csw = ((tk * 4 + l16) ^ l7) << 4;
            bf16x8 apA = *(const bf16x8*)(psw + l15 * 128 + csw);
            bf16x8 apB = *(const bf16x8*)(psw + (16 + l15) * 128 + csw);
            accl[0] = __builtin_amdgcn_mfma_f32_16x16x32_bf16(apA, ones, accl[0], 0, 0, 0);
            accl[1] = __builtin_amdgcn_mfma_f32_16x16x32_bf16(apB, ones, accl[1], 0, 0, 0);
            #pragma unroll
            for (int nd = 0; nd < 4; nd++) {
                bf16x8 bv = *(const bf16x8*)(vbuf + (nd * 16 + l15) * 128 + csw);
                acc[0][nd] = __builtin_amdgcn_mfma_f32_16x16x32_bf16(apA, bv, acc[0][nd], 0, 0, 0);
                acc[1][nd] = __builtin_amdgcn_mfma_f32_16x16x32_bf16(apB, bv, acc[1][nd], 0, 0, 0);
            }
        }
        __builtin_amdgcn_s_setprio(0);

        sv0 = nv0; sv1 = nv1;
        #pragma unroll
        for (int tb = 0; tb < 4; tb++) kfr[tb] = nkf[tb];
    }

    // ---- combine halves: waves 4-7 hand their partials to waves 0-3 via LDS
    __syncthreads();                               // all vt/ps reads complete
    float* xch = (float*)lds;                      // 40 KB scratch (vt + low ps, all dead)
    if (wave >= 4) {
        float* dst = xch + ((size_t)((wave - 4) * 64 + lane)) * 40;
        #pragma unroll
        for (int g = 0; g < 2; g++)
            #pragma unroll
            for (int nd = 0; nd < 4; nd++)
                *(f32x4*)(dst + (g * 4 + nd) * 4) = acc[g][nd];
        *(f32x4*)(dst + 32) = accl[0];
        *(f32x4*)(dst + 36) = accl[1];
    }
    __syncthreads();
    if (wave < 4) {
        float* src = xch + ((size_t)(wave * 64 + lane)) * 40;
        #pragma unroll
        for (int g = 0; g < 2; g++)
            #pragma unroll
            for (int nd = 0; nd < 4; nd++)
                acc[g][nd] += *(const f32x4*)(src + (g * 4 + nd) * 4);
        accl[0] += *(const f32x4*)(src + 32);
        accl[1] += *(const f32x4*)(src + 36);

        #pragma unroll
        for (int g = 0; g < 2; g++) {
            #pragma unroll
            for (int r = 0; r < 4; r++) {
                float linv = 1.f / accl[g][r];
                int q = s0 + g * 16 + l16 * 4 + r;
                size_t row = (size_t)(b * SS + q) * HH + h * HDD;
                #pragma unroll
                for (int nd = 0; nd < 4; nd++)
                    attnb[row + nd * 16 + l15] = f2bf(acc[g][nd][r] * linv);
            }
        }
    }
}

extern "C" void kernel_launch(void* const* d_in, const int* in_sizes, int n_in,
                              void* d_out, int out_size, void* d_ws, size_t ws_size,
                              hipStream_t stream)
{
    const float* x  = (const float*)d_in[0];
    const float* Wq = (const float*)d_in[1];
    const float* Wk = (const float*)d_in[2];
    const float* Wv = (const float*)d_in[3];
    const float* Wo = (const float*)d_in[4];
    const float* bq = (const float*)d_in[5];
    const float* bk = (const float*)d_in[6];
    const float* bv = (const float*)d_in[7];
    const float* bo = (const float*)d_in[8];

    unsigned short* qfb   = (unsigned short*)d_ws;     // 524288
    unsigned short* kfb   = qfb + 524288;              // 524288
    unsigned short* xb    = kfb + 524288;              // 4194304 (aliased w/ attnb)
    unsigned short* attnb = xb;                        // alias: xb dead after fused_mid
    unsigned short* Wvb   = xb + 4194304;              // 1048576
    unsigned short* Wob   = Wvb + 1048576;             // 1048576
    unsigned short* Vt    = Wob + 1048576;             // 4194304
    unsigned short* wselb  = Vt + 4194304;             // 65536
    float*          bselws = (float*)(wselb + 65536);  // 64

    cvt_kernel<<<2112, 256, 0, stream>>>(x, Wv, Wo, Wq, Wk, bq, bk, xb, Wvb, Wob, wselb, bselws);
    fused_mid<<<640, 256, 0, stream>>>(xb, Wvb, bv, Vt, wselb, bselws, qfb, kfb);
    attn_mfma<<<dim3(16, 32), 512, 0, stream>>>(qfb, kfb, Vt, attnb);
    gemm_out<<<512, 256, 0, stream>>>(attnb, Wob, bo, (float*)d_out);
}